// Round 6
// baseline (122.106 us; speedup 1.0000x reference)
//
#include <hip/hip_runtime.h>
#include <stdint.h>

// OutliersQLinearUnstruct: out[b][o] = sum_i x[b][i]*w_eff[o][i] + bias[o]
//   w_eff = mask ? w : scale_o * sign(w - mean_o)
//   mean_o = mean(wz_row), scale_o = mean(|wz_row|), wz = mask ? 0 : w
// OC=11008, IC=4096, B=32. x/w/bias f32; mask int32 (nonzero = outlier).
//
// R6: fuse processes 2 rows/block; ALL 16 global loads issued before a
//     __builtin_amdgcn_sched_barrier(0) pin (defeats compiler load-sinking —
//     R5's source-level phase split was re-sunk, VGPR stayed 20). Mask regs
//     die early into nibble bits; w regs stay live across the stats barrier.
//     K2 MFMA bf16 GEMM (split-K=8) and K3 reduce unchanged.

#define OC 11008
#define IC 4096
#define BATCH 32
#define SKM 8              // split-K for MFMA gemm
#define SKF 4              // split-K for fallback gemv

typedef __attribute__((ext_vector_type(8))) short short8;
typedef __attribute__((ext_vector_type(4))) float floatx4;

static __device__ __forceinline__ unsigned short f2bf(float f) {
  uint32_t u = __builtin_bit_cast(uint32_t, f);
  uint32_t r = (u + 0x7fffu + ((u >> 16) & 1u)) >> 16;
  return (unsigned short)r;
}

// ---------------- K1: fused stats + transform + bf16 stores ----------------
// blocks 0..31: x-cast (one b-row each). blocks 32..32+OC/2-1: 2 w-rows each.
__global__ __launch_bounds__(256) void fuse_kernel(
    const float* __restrict__ w, const int* __restrict__ mask,
    const float* __restrict__ x, unsigned short* __restrict__ weff,
    unsigned short* __restrict__ xbf) {
  const int blk = blockIdx.x;
  const int t = threadIdx.x;

  if (blk < BATCH) {  // x cast: row b = blk
    const float* xr = x + (size_t)blk * IC;
    unsigned short* xo = xbf + (size_t)blk * IC;
    float4 xv[4];
#pragma unroll
    for (int q = 0; q < 4; ++q)
      xv[q] = *reinterpret_cast<const float4*>(xr + (q << 10) + (t << 2));
#pragma unroll
    for (int q = 0; q < 4; ++q) {
      ushort4 u;
      u.x = f2bf(xv[q].x); u.y = f2bf(xv[q].y);
      u.z = f2bf(xv[q].z); u.w = f2bf(xv[q].w);
      *reinterpret_cast<ushort4*>(xo + (q << 10) + (t << 2)) = u;
    }
    return;
  }

  const int row0 = (blk - BATCH) * 2;
  const float* wr = w + (size_t)row0 * IC;
  const int* mr = mask + (size_t)row0 * IC;

  // Phase A: ALL 16 loads issued before the scheduling pin.
  float4 wv[2][4];
  int4 mv[2][4];
#pragma unroll
  for (int r = 0; r < 2; ++r)
#pragma unroll
    for (int q = 0; q < 4; ++q)
      wv[r][q] = *reinterpret_cast<const float4*>(
          wr + (size_t)r * IC + (q << 10) + (t << 2));
#pragma unroll
  for (int r = 0; r < 2; ++r)
#pragma unroll
    for (int q = 0; q < 4; ++q)
      mv[r][q] = *reinterpret_cast<const int4*>(
          mr + (size_t)r * IC + (q << 10) + (t << 2));
  __builtin_amdgcn_sched_barrier(0);

  // Phase B1: mask -> 16 nibble bits per row; mask registers die here.
  uint32_t nib[2];
#pragma unroll
  for (int r = 0; r < 2; ++r) {
    uint32_t nb = 0;
#pragma unroll
    for (int q = 0; q < 4; ++q) {
      nb |= (uint32_t)(mv[r][q].x != 0) << (q * 4 + 0);
      nb |= (uint32_t)(mv[r][q].y != 0) << (q * 4 + 1);
      nb |= (uint32_t)(mv[r][q].z != 0) << (q * 4 + 2);
      nb |= (uint32_t)(mv[r][q].w != 0) << (q * 4 + 3);
    }
    nib[r] = nb;
  }
  __builtin_amdgcn_sched_barrier(0);

  // Phase B2: stats for both rows.
  float s1[2], s2[2];
#pragma unroll
  for (int r = 0; r < 2; ++r) {
    float a = 0.f, b = 0.f;
    const uint32_t nb = nib[r];
#pragma unroll
    for (int q = 0; q < 4; ++q) {
      const float z0 = (nb >> (q * 4 + 0)) & 1u ? 0.f : wv[r][q].x;
      const float z1 = (nb >> (q * 4 + 1)) & 1u ? 0.f : wv[r][q].y;
      const float z2 = (nb >> (q * 4 + 2)) & 1u ? 0.f : wv[r][q].z;
      const float z3 = (nb >> (q * 4 + 3)) & 1u ? 0.f : wv[r][q].w;
      a += z0 + z1 + z2 + z3;
      b += fabsf(z0) + fabsf(z1) + fabsf(z2) + fabsf(z3);
    }
    s1[r] = a;
    s2[r] = b;
  }

#pragma unroll
  for (int off = 32; off > 0; off >>= 1) {
#pragma unroll
    for (int r = 0; r < 2; ++r) {
      s1[r] += __shfl_down(s1[r], off);
      s2[r] += __shfl_down(s2[r], off);
    }
  }
  __shared__ float red[4][4];  // [wave][{s1_0,s2_0,s1_1,s2_1}]
  if ((t & 63) == 0) {
    red[t >> 6][0] = s1[0];
    red[t >> 6][1] = s2[0];
    red[t >> 6][2] = s1[1];
    red[t >> 6][3] = s2[1];
  }
  __syncthreads();
  const float mean0 = (red[0][0] + red[1][0] + red[2][0] + red[3][0]) * (1.0f / IC);
  const float scl0  = (red[0][1] + red[1][1] + red[2][1] + red[3][1]) * (1.0f / IC);
  const float mean1 = (red[0][2] + red[1][2] + red[2][2] + red[3][2]) * (1.0f / IC);
  const float scl1  = (red[0][3] + red[1][3] + red[2][3] + red[3][3]) * (1.0f / IC);
  const float means[2] = {mean0, mean1};
  const float scls[2] = {scl0, scl1};

  // Phase C: transform + store from still-live registers.
  unsigned short* wo = weff + (size_t)row0 * IC;
#pragma unroll
  for (int r = 0; r < 2; ++r) {
    const float mean = means[r], scale = scls[r];
    const uint32_t nb = nib[r];
#pragma unroll
    for (int q = 0; q < 4; ++q) {
      float4 v = wv[r][q];
      v.x = (nb >> (q * 4 + 0)) & 1u ? v.x : copysignf(scale, v.x - mean);
      v.y = (nb >> (q * 4 + 1)) & 1u ? v.y : copysignf(scale, v.y - mean);
      v.z = (nb >> (q * 4 + 2)) & 1u ? v.z : copysignf(scale, v.z - mean);
      v.w = (nb >> (q * 4 + 3)) & 1u ? v.w : copysignf(scale, v.w - mean);
      ushort4 u;
      u.x = f2bf(v.x); u.y = f2bf(v.y); u.z = f2bf(v.z); u.w = f2bf(v.w);
      *reinterpret_cast<ushort4*>(wo + (size_t)r * IC + (q << 10) + (t << 2)) = u;
    }
  }
}

// ---------------- K2: bf16 MFMA GEMM, split-K ----------------
// block = 4 waves; wave wv owns cols [tile*64 + wv*16, +16), K-chunk sk*512.
// D: col = lane&15, row(b) = (lane>>4)*4 + reg  [m89 layout].
__global__ __launch_bounds__(256) void mfma_kernel(
    const unsigned short* __restrict__ weff,
    const unsigned short* __restrict__ xbf, float* __restrict__ part) {
  const int bx = blockIdx.x;
  const int tile = bx >> 3;
  const int sk = bx & 7;
  const int t = threadIdx.x;
  const int wv = t >> 6;
  const int l = t & 63;
  const int l15 = l & 15, l4 = l >> 4;

  const int o = tile * 64 + wv * 16 + l15;
  const int k0 = sk * (IC / SKM) + l4 * 8;

  const unsigned short* bp = weff + (size_t)o * IC + k0;
  const unsigned short* ap0 = xbf + (size_t)l15 * IC + k0;
  const unsigned short* ap1 = xbf + (size_t)(16 + l15) * IC + k0;

  floatx4 acc0 = {0.f, 0.f, 0.f, 0.f};
  floatx4 acc1 = {0.f, 0.f, 0.f, 0.f};
#pragma unroll 4
  for (int kk = 0; kk < (IC / SKM) / 32; ++kk) {  // 16 iters
    const short8 bf = *reinterpret_cast<const short8*>(bp + kk * 32);
    const short8 a0 = *reinterpret_cast<const short8*>(ap0 + kk * 32);
    const short8 a1 = *reinterpret_cast<const short8*>(ap1 + kk * 32);
    acc0 = __builtin_amdgcn_mfma_f32_16x16x32_bf16(a0, bf, acc0, 0, 0, 0);
    acc1 = __builtin_amdgcn_mfma_f32_16x16x32_bf16(a1, bf, acc1, 0, 0, 0);
  }

  float* pb = part + (size_t)sk * (BATCH * OC);
#pragma unroll
  for (int r = 0; r < 4; ++r) {
    const int b0 = l4 * 4 + r;
    pb[(size_t)b0 * OC + o] = acc0[r];
    pb[(size_t)(b0 + 16) * OC + o] = acc1[r];
  }
}

__global__ __launch_bounds__(256) void reduce_kernel(
    const float* __restrict__ part, const float* __restrict__ bias,
    float* __restrict__ out, int nsk) {
  const int idx = blockIdx.x * 256 + threadIdx.x;
  if (idx < BATCH * OC) {
    const int o = idx % OC;
    float v = bias[o];
    for (int sk = 0; sk < nsk; ++sk) v += part[(size_t)sk * (BATCH * OC) + idx];
    out[idx] = v;
  }
}

// ---------------- Fallback (f32 VALU path, known-correct) ----------------
__global__ __launch_bounds__(256) void stats_kernel_fb(
    const int* __restrict__ mask, const float* __restrict__ w,
    float2* __restrict__ stats) {
  const int o = blockIdx.x;
  const int t = threadIdx.x;
  const float* wr = w + (size_t)o * IC;
  const int* mr = mask + (size_t)o * IC;
  float s1 = 0.f, s2 = 0.f;
#pragma unroll
  for (int q = 0; q < 4; ++q) {
    const int i = (q << 10) + (t << 2);
    const float4 wv = *reinterpret_cast<const float4*>(wr + i);
    const int4 mv = *reinterpret_cast<const int4*>(mr + i);
    const float z0 = mv.x ? 0.f : wv.x, z1 = mv.y ? 0.f : wv.y;
    const float z2 = mv.z ? 0.f : wv.z, z3 = mv.w ? 0.f : wv.w;
    s1 += z0 + z1 + z2 + z3;
    s2 += fabsf(z0) + fabsf(z1) + fabsf(z2) + fabsf(z3);
  }
#pragma unroll
  for (int off = 32; off > 0; off >>= 1) {
    s1 += __shfl_down(s1, off);
    s2 += __shfl_down(s2, off);
  }
  __shared__ float r1[4], r2[4];
  if ((t & 63) == 0) { r1[t >> 6] = s1; r2[t >> 6] = s2; }
  __syncthreads();
  if (t == 0)
    stats[o] = make_float2((r1[0] + r1[1] + r1[2] + r1[3]) * (1.0f / IC),
                           (r2[0] + r2[1] + r2[2] + r2[3]) * (1.0f / IC));
}

__global__ __launch_bounds__(256) void gemv_kernel_fb(
    const float* __restrict__ x, const float* __restrict__ w,
    const int* __restrict__ mask, const float2* __restrict__ stats,
    float* __restrict__ part) {
  const int bx = blockIdx.x;
  const int tile = bx >> 2;
  const int sk = bx & 3;
  const int t = threadIdx.x;
  const int wvid = t >> 6;
  const int lane = t & 63;
  const int il = lane & 15;
  const int bg = lane >> 4;
  const int row0 = tile * 32 + wvid * 8;
  const int i0 = sk * (IC / SKF);
  const float* wr0 = w + (size_t)row0 * IC;
  const int* mk0 = mask + (size_t)row0 * IC;
  const float* xb = x + (size_t)(bg * 8) * IC;

  float2 stv[8];
#pragma unroll
  for (int r = 0; r < 8; ++r) stv[r] = stats[row0 + r];
  float acc[8][8];
#pragma unroll
  for (int r = 0; r < 8; ++r)
#pragma unroll
    for (int j = 0; j < 8; ++j) acc[r][j] = 0.f;

  for (int s_ = 0; s_ < (IC / SKF) / 64; ++s_) {
    const int i = i0 + (s_ << 6) + (il << 2);
    float4 wf[8];
#pragma unroll
    for (int r = 0; r < 8; ++r) {
      wf[r] = *reinterpret_cast<const float4*>(wr0 + (size_t)r * IC + i);
      const int4 mv = *reinterpret_cast<const int4*>(mk0 + (size_t)r * IC + i);
      const float m = stv[r].x, sc = stv[r].y;
      wf[r].x = mv.x ? wf[r].x : copysignf(sc, wf[r].x - m);
      wf[r].y = mv.y ? wf[r].y : copysignf(sc, wf[r].y - m);
      wf[r].z = mv.z ? wf[r].z : copysignf(sc, wf[r].z - m);
      wf[r].w = mv.w ? wf[r].w : copysignf(sc, wf[r].w - m);
    }
#pragma unroll
    for (int j = 0; j < 8; ++j) {
      const float4 xv = *reinterpret_cast<const float4*>(xb + (size_t)j * IC + i);
#pragma unroll
      for (int r = 0; r < 8; ++r)
        acc[r][j] += wf[r].x * xv.x + wf[r].y * xv.y + wf[r].z * xv.z +
                     wf[r].w * xv.w;
    }
  }
#pragma unroll
  for (int off = 8; off >= 1; off >>= 1)
#pragma unroll
    for (int r = 0; r < 8; ++r)
#pragma unroll
      for (int j = 0; j < 8; ++j) acc[r][j] += __shfl_xor(acc[r][j], off);
  if (il == 0)
#pragma unroll
    for (int r = 0; r < 8; ++r)
#pragma unroll
      for (int j = 0; j < 8; ++j)
        part[(size_t)sk * (BATCH * OC) + (size_t)(bg * 8 + j) * OC +
             (row0 + r)] = acc[r][j];
}

// ---------------- launch ----------------
extern "C" void kernel_launch(void* const* d_in, const int* in_sizes, int n_in,
                              void* d_out, int out_size, void* d_ws,
                              size_t ws_size, hipStream_t stream) {
  const float* x = (const float*)d_in[0];
  const float* w = (const float*)d_in[1];
  const float* bias = (const float*)d_in[2];
  const int* mask = (const int*)d_in[3];
  float* out = (float*)d_out;

  const size_t weff_b = (size_t)OC * IC * 2;          // 90,177,536
  const size_t xbf_b = (size_t)BATCH * IC * 2;        // 262,144
  const size_t part_b = (size_t)SKM * BATCH * OC * 4; // 11,272,192

  if (ws_size >= weff_b + xbf_b + part_b) {
    unsigned short* weff = (unsigned short*)d_ws;
    unsigned short* xbf = (unsigned short*)((char*)d_ws + weff_b);
    float* part = (float*)((char*)d_ws + weff_b + xbf_b);

    fuse_kernel<<<BATCH + OC / 2, 256, 0, stream>>>(w, mask, x, weff, xbf);
    mfma_kernel<<<(OC / 64) * SKM, 256, 0, stream>>>(weff, xbf, part);
    reduce_kernel<<<(BATCH * OC + 255) / 256, 256, 0, stream>>>(part, bias, out,
                                                                SKM);
  } else {
    float2* stats = (float2*)d_ws;
    float* part = (float*)((char*)d_ws + (size_t)OC * sizeof(float2));
    stats_kernel_fb<<<OC, 256, 0, stream>>>(mask, w, stats);
    gemv_kernel_fb<<<(OC / 32) * SKF, 256, 0, stream>>>(x, w, mask, stats, part);
    reduce_kernel<<<(BATCH * OC + 255) / 256, 256, 0, stream>>>(part, bias, out,
                                                                SKF);
  }
}

// Round 8
// 111.121 us; speedup vs baseline: 1.0989x; 1.0989x over previous
//
#include <hip/hip_runtime.h>
#include <stdint.h>

// OutliersQLinearUnstruct: out[b][o] = sum_i x[b][i]*w_eff[o][i] + bias[o]
//   w_eff = mask ? w : scale_o * sign(w - mean_o)
//   mean_o = mean(wz_row), scale_o = mean(|wz_row|), wz = mask ? 0 : w
// OC=11008, IC=4096, B=32. x/w/bias f32; mask int32 (nonzero = outlier).
//
// R8 = R7 with the nontemporal-load type fixed (clang ext_vector int4, not
//     HIP_vector_type). fuse = ONE WAVE PER ROW, no LDS, no __syncthreads.
//     Each lane owns 64 elems (16 float4 w + 16 int4 mask folded to 64 bits).
//     Stats via 6-step shfl_xor butterfly. Mask loads nontemporal.
//     K2 MFMA bf16 GEMM (split-K=8) and K3 reduce unchanged.

#define OC 11008
#define IC 4096
#define BATCH 32
#define SKM 8              // split-K for MFMA gemm
#define SKF 4              // split-K for fallback gemv

typedef __attribute__((ext_vector_type(8))) short short8;
typedef __attribute__((ext_vector_type(4))) float floatx4;
typedef __attribute__((ext_vector_type(4))) int intx4;

static __device__ __forceinline__ unsigned short f2bf(float f) {
  uint32_t u = __builtin_bit_cast(uint32_t, f);
  uint32_t r = (u + 0x7fffu + ((u >> 16) & 1u)) >> 16;
  return (unsigned short)r;
}

// ---------------- K1: fused stats + transform + bf16 stores ----------------
// blocks 0..7: x-cast (4 rows/block, one per wave).
// blocks 8..8+OC/4-1: w rows, one row per wave (4 rows/block).
__global__ __launch_bounds__(256) void fuse_kernel(
    const float* __restrict__ w, const int* __restrict__ mask,
    const float* __restrict__ x, unsigned short* __restrict__ weff,
    unsigned short* __restrict__ xbf) {
  const int blk = blockIdx.x;
  const int t = threadIdx.x;
  const int lane = t & 63;
  const int wvid = t >> 6;

  if (blk < 8) {  // x cast: row b = blk*4 + wvid
    const int b = blk * 4 + wvid;
    const float* xr = x + (size_t)b * IC;
    unsigned short* xo = xbf + (size_t)b * IC;
#pragma unroll
    for (int q = 0; q < 16; ++q) {
      const int i = (q << 8) + (lane << 2);
      const float4 v = *reinterpret_cast<const float4*>(xr + i);
      ushort4 u;
      u.x = f2bf(v.x); u.y = f2bf(v.y); u.z = f2bf(v.z); u.w = f2bf(v.w);
      *reinterpret_cast<ushort4*>(xo + i) = u;
    }
    return;
  }

  const int row = (blk - 8) * 4 + wvid;
  const float* wr = w + (size_t)row * IC;
  const int* mr = mask + (size_t)row * IC;

  // Load + fold: per-lane 16 float4 (live) + 16 int4 -> 64 bits (transient).
  float4 wv[16];
  uint32_t bits_lo = 0, bits_hi = 0;
  float s1 = 0.f, s2 = 0.f;
#pragma unroll
  for (int q = 0; q < 16; ++q) {
    const int i = (q << 8) + (lane << 2);
    wv[q] = *reinterpret_cast<const float4*>(wr + i);
    const intx4 mv =
        __builtin_nontemporal_load(reinterpret_cast<const intx4*>(mr + i));
    const uint32_t nb = (uint32_t)(mv.x != 0) | ((uint32_t)(mv.y != 0) << 1) |
                        ((uint32_t)(mv.z != 0) << 2) |
                        ((uint32_t)(mv.w != 0) << 3);
    if (q < 8)
      bits_lo |= nb << (q * 4);
    else
      bits_hi |= nb << ((q - 8) * 4);
    const float z0 = (nb & 1u) ? 0.f : wv[q].x;
    const float z1 = (nb & 2u) ? 0.f : wv[q].y;
    const float z2 = (nb & 4u) ? 0.f : wv[q].z;
    const float z3 = (nb & 8u) ? 0.f : wv[q].w;
    s1 += z0 + z1 + z2 + z3;
    s2 += fabsf(z0) + fabsf(z1) + fabsf(z2) + fabsf(z3);
  }

  // 64-lane butterfly: every lane ends with the full-row sums.
#pragma unroll
  for (int off = 1; off < 64; off <<= 1) {
    s1 += __shfl_xor(s1, off);
    s2 += __shfl_xor(s2, off);
  }
  const float mean = s1 * (1.0f / IC);
  const float scale = s2 * (1.0f / IC);

  // Transform + store.
  unsigned short* wo = weff + (size_t)row * IC;
#pragma unroll
  for (int q = 0; q < 16; ++q) {
    const uint32_t nb =
        ((q < 8) ? (bits_lo >> (q * 4)) : (bits_hi >> ((q - 8) * 4))) & 0xFu;
    float4 v = wv[q];
    v.x = (nb & 1u) ? v.x : copysignf(scale, v.x - mean);
    v.y = (nb & 2u) ? v.y : copysignf(scale, v.y - mean);
    v.z = (nb & 4u) ? v.z : copysignf(scale, v.z - mean);
    v.w = (nb & 8u) ? v.w : copysignf(scale, v.w - mean);
    ushort4 u;
    u.x = f2bf(v.x); u.y = f2bf(v.y); u.z = f2bf(v.z); u.w = f2bf(v.w);
    *reinterpret_cast<ushort4*>(wo + (q << 8) + (lane << 2)) = u;
  }
}

// ---------------- K2: bf16 MFMA GEMM, split-K ----------------
// block = 4 waves; wave wv owns cols [tile*64 + wv*16, +16), K-chunk sk*512.
// D: col = lane&15, row(b) = (lane>>4)*4 + reg  [m89 layout].
__global__ __launch_bounds__(256) void mfma_kernel(
    const unsigned short* __restrict__ weff,
    const unsigned short* __restrict__ xbf, float* __restrict__ part) {
  const int bx = blockIdx.x;
  const int tile = bx >> 3;
  const int sk = bx & 7;
  const int t = threadIdx.x;
  const int wv = t >> 6;
  const int l = t & 63;
  const int l15 = l & 15, l4 = l >> 4;

  const int o = tile * 64 + wv * 16 + l15;
  const int k0 = sk * (IC / SKM) + l4 * 8;

  const unsigned short* bp = weff + (size_t)o * IC + k0;
  const unsigned short* ap0 = xbf + (size_t)l15 * IC + k0;
  const unsigned short* ap1 = xbf + (size_t)(16 + l15) * IC + k0;

  floatx4 acc0 = {0.f, 0.f, 0.f, 0.f};
  floatx4 acc1 = {0.f, 0.f, 0.f, 0.f};
#pragma unroll 4
  for (int kk = 0; kk < (IC / SKM) / 32; ++kk) {  // 16 iters
    const short8 bf = *reinterpret_cast<const short8*>(bp + kk * 32);
    const short8 a0 = *reinterpret_cast<const short8*>(ap0 + kk * 32);
    const short8 a1 = *reinterpret_cast<const short8*>(ap1 + kk * 32);
    acc0 = __builtin_amdgcn_mfma_f32_16x16x32_bf16(a0, bf, acc0, 0, 0, 0);
    acc1 = __builtin_amdgcn_mfma_f32_16x16x32_bf16(a1, bf, acc1, 0, 0, 0);
  }

  float* pb = part + (size_t)sk * (BATCH * OC);
#pragma unroll
  for (int r = 0; r < 4; ++r) {
    const int b0 = l4 * 4 + r;
    pb[(size_t)b0 * OC + o] = acc0[r];
    pb[(size_t)(b0 + 16) * OC + o] = acc1[r];
  }
}

__global__ __launch_bounds__(256) void reduce_kernel(
    const float* __restrict__ part, const float* __restrict__ bias,
    float* __restrict__ out, int nsk) {
  const int idx = blockIdx.x * 256 + threadIdx.x;
  if (idx < BATCH * OC) {
    const int o = idx % OC;
    float v = bias[o];
    for (int sk = 0; sk < nsk; ++sk) v += part[(size_t)sk * (BATCH * OC) + idx];
    out[idx] = v;
  }
}

// ---------------- Fallback (f32 VALU path, known-correct) ----------------
__global__ __launch_bounds__(256) void stats_kernel_fb(
    const int* __restrict__ mask, const float* __restrict__ w,
    float2* __restrict__ stats) {
  const int o = blockIdx.x;
  const int t = threadIdx.x;
  const float* wr = w + (size_t)o * IC;
  const int* mr = mask + (size_t)o * IC;
  float s1 = 0.f, s2 = 0.f;
#pragma unroll
  for (int q = 0; q < 4; ++q) {
    const int i = (q << 10) + (t << 2);
    const float4 wv = *reinterpret_cast<const float4*>(wr + i);
    const int4 mv = *reinterpret_cast<const int4*>(mr + i);
    const float z0 = mv.x ? 0.f : wv.x, z1 = mv.y ? 0.f : wv.y;
    const float z2 = mv.z ? 0.f : wv.z, z3 = mv.w ? 0.f : wv.w;
    s1 += z0 + z1 + z2 + z3;
    s2 += fabsf(z0) + fabsf(z1) + fabsf(z2) + fabsf(z3);
  }
#pragma unroll
  for (int off = 32; off > 0; off >>= 1) {
    s1 += __shfl_down(s1, off);
    s2 += __shfl_down(s2, off);
  }
  __shared__ float r1[4], r2[4];
  if ((t & 63) == 0) { r1[t >> 6] = s1; r2[t >> 6] = s2; }
  __syncthreads();
  if (t == 0)
    stats[o] = make_float2((r1[0] + r1[1] + r1[2] + r1[3]) * (1.0f / IC),
                           (r2[0] + r2[1] + r2[2] + r2[3]) * (1.0f / IC));
}

__global__ __launch_bounds__(256) void gemv_kernel_fb(
    const float* __restrict__ x, const float* __restrict__ w,
    const int* __restrict__ mask, const float2* __restrict__ stats,
    float* __restrict__ part) {
  const int bx = blockIdx.x;
  const int tile = bx >> 2;
  const int sk = bx & 3;
  const int t = threadIdx.x;
  const int wvid = t >> 6;
  const int lane = t & 63;
  const int il = lane & 15;
  const int bg = lane >> 4;
  const int row0 = tile * 32 + wvid * 8;
  const int i0 = sk * (IC / SKF);
  const float* wr0 = w + (size_t)row0 * IC;
  const int* mk0 = mask + (size_t)row0 * IC;
  const float* xb = x + (size_t)(bg * 8) * IC;

  float2 stv[8];
#pragma unroll
  for (int r = 0; r < 8; ++r) stv[r] = stats[row0 + r];
  float acc[8][8];
#pragma unroll
  for (int r = 0; r < 8; ++r)
#pragma unroll
    for (int j = 0; j < 8; ++j) acc[r][j] = 0.f;

  for (int s_ = 0; s_ < (IC / SKF) / 64; ++s_) {
    const int i = i0 + (s_ << 6) + (il << 2);
    float4 wf[8];
#pragma unroll
    for (int r = 0; r < 8; ++r) {
      wf[r] = *reinterpret_cast<const float4*>(wr0 + (size_t)r * IC + i);
      const int4 mv = *reinterpret_cast<const int4*>(mk0 + (size_t)r * IC + i);
      const float m = stv[r].x, sc = stv[r].y;
      wf[r].x = mv.x ? wf[r].x : copysignf(sc, wf[r].x - m);
      wf[r].y = mv.y ? wf[r].y : copysignf(sc, wf[r].y - m);
      wf[r].z = mv.z ? wf[r].z : copysignf(sc, wf[r].z - m);
      wf[r].w = mv.w ? wf[r].w : copysignf(sc, wf[r].w - m);
    }
#pragma unroll
    for (int j = 0; j < 8; ++j) {
      const float4 xv = *reinterpret_cast<const float4*>(xb + (size_t)j * IC + i);
#pragma unroll
      for (int r = 0; r < 8; ++r)
        acc[r][j] += wf[r].x * xv.x + wf[r].y * xv.y + wf[r].z * xv.z +
                     wf[r].w * xv.w;
    }
  }
#pragma unroll
  for (int off = 8; off >= 1; off >>= 1)
#pragma unroll
    for (int r = 0; r < 8; ++r)
#pragma unroll
      for (int j = 0; j < 8; ++j) acc[r][j] += __shfl_xor(acc[r][j], off);
  if (il == 0)
#pragma unroll
    for (int r = 0; r < 8; ++r)
#pragma unroll
      for (int j = 0; j < 8; ++j)
        part[(size_t)sk * (BATCH * OC) + (size_t)(bg * 8 + j) * OC +
             (row0 + r)] = acc[r][j];
}

// ---------------- launch ----------------
extern "C" void kernel_launch(void* const* d_in, const int* in_sizes, int n_in,
                              void* d_out, int out_size, void* d_ws,
                              size_t ws_size, hipStream_t stream) {
  const float* x = (const float*)d_in[0];
  const float* w = (const float*)d_in[1];
  const float* bias = (const float*)d_in[2];
  const int* mask = (const int*)d_in[3];
  float* out = (float*)d_out;

  const size_t weff_b = (size_t)OC * IC * 2;          // 90,177,536
  const size_t xbf_b = (size_t)BATCH * IC * 2;        // 262,144
  const size_t part_b = (size_t)SKM * BATCH * OC * 4; // 11,272,192

  if (ws_size >= weff_b + xbf_b + part_b) {
    unsigned short* weff = (unsigned short*)d_ws;
    unsigned short* xbf = (unsigned short*)((char*)d_ws + weff_b);
    float* part = (float*)((char*)d_ws + weff_b + xbf_b);

    fuse_kernel<<<8 + OC / 4, 256, 0, stream>>>(w, mask, x, weff, xbf);
    mfma_kernel<<<(OC / 64) * SKM, 256, 0, stream>>>(weff, xbf, part);
    reduce_kernel<<<(BATCH * OC + 255) / 256, 256, 0, stream>>>(part, bias, out,
                                                                SKM);
  } else {
    float2* stats = (float2*)d_ws;
    float* part = (float*)((char*)d_ws + (size_t)OC * sizeof(float2));
    stats_kernel_fb<<<OC, 256, 0, stream>>>(mask, w, stats);
    gemv_kernel_fb<<<(OC / 32) * SKF, 256, 0, stream>>>(x, w, mask, stats, part);
    reduce_kernel<<<(BATCH * OC + 255) / 256, 256, 0, stream>>>(part, bias, out,
                                                                SKF);
  }
}